// Round 6
// baseline (156.232 us; speedup 1.0000x reference)
//
#include <hip/hip_runtime.h>

// COO SpMM, rows sorted: out[r] = sum_{e: rows[e]==r} vals[e] * embeds[cols[e]]
// N=50000, E=800000, D=64 fp32.
//
// R6: MEASUREMENT ROUND. fp16 (R5) tied fp32 (R4) => gather-byte halving is
// not the bottleneck; suspicion is most of the 98us window is harness reset
// (268MB ws re-poison ~44us + dozens of restore dispatches). Both kernels are
// idempotent (pure overwrite), so launch each 3x: kernel time K shows up as
// 2K extra in dur_us => K = (dur - 96)/2. cvt dropped (no benefit, fp32 has
// 2x the absmax margin).

#define D_FEAT 64
#define BLOCK 256

__global__ __launch_bounds__(BLOCK) void build_row_ptr_edges(
    const int* __restrict__ rows, int* __restrict__ row_ptr,
    int n_nodes, int n_edges)
{
    const int e = blockIdx.x * BLOCK + threadIdx.x;
    if (e >= n_edges) return;
    const int r  = rows[e];
    const int rp = (e == 0) ? -1 : rows[e - 1];
    for (int v = rp + 1; v <= r; ++v) row_ptr[v] = e;
    if (e == n_edges - 1)
        for (int v = r + 1; v <= n_nodes; ++v) row_ptr[v] = n_edges;
}

__global__ __launch_bounds__(BLOCK) void spmm_row_strip16(
    const int* __restrict__ row_ptr,
    const int* __restrict__ cols,
    const float* __restrict__ vals,
    const float* __restrict__ embeds,
    float* __restrict__ out,
    int n_nodes)
{
    const int wave = (int)((blockIdx.x * (unsigned)BLOCK + threadIdx.x) >> 6);
    if (wave >= n_nodes) return;
    const int lane = (int)(threadIdx.x & 63u);
    const int sub  = lane >> 4;   // edge slot 0..3
    const int f4   = lane & 15;   // float4 slot within the 64-float row

    const int s = row_ptr[wave];
    const int t = row_ptr[wave + 1];
    if (s >= t) {
        if (lane < 16)
            ((float4*)(out + (size_t)wave * D_FEAT))[f4] = make_float4(0.f,0.f,0.f,0.f);
        return;
    }

    float4 acc = make_float4(0.f, 0.f, 0.f, 0.f);

    for (int e = s; e < t; e += 16) {
        const int tm1 = t - 1;
        const int i0 = e + sub, i1 = i0 + 4, i2 = i0 + 8, i3 = i0 + 12;
        const int j0 = i0 < tm1 ? i0 : tm1;
        const int j1 = i1 < tm1 ? i1 : tm1;
        const int j2 = i2 < tm1 ? i2 : tm1;
        const int j3 = i3 < tm1 ? i3 : tm1;
        const int c0 = cols[j0], c1 = cols[j1], c2 = cols[j2], c3 = cols[j3];
        float v0 = vals[j0], v1 = vals[j1], v2 = vals[j2], v3 = vals[j3];
        if (i0 > tm1) v0 = 0.f;
        if (i1 > tm1) v1 = 0.f;
        if (i2 > tm1) v2 = 0.f;
        if (i3 > tm1) v3 = 0.f;
        const float4 x0 = ((const float4*)(embeds + (size_t)c0 * D_FEAT))[f4];
        const float4 x1 = ((const float4*)(embeds + (size_t)c1 * D_FEAT))[f4];
        const float4 x2 = ((const float4*)(embeds + (size_t)c2 * D_FEAT))[f4];
        const float4 x3 = ((const float4*)(embeds + (size_t)c3 * D_FEAT))[f4];
        acc.x = fmaf(v0, x0.x, acc.x); acc.y = fmaf(v0, x0.y, acc.y);
        acc.z = fmaf(v0, x0.z, acc.z); acc.w = fmaf(v0, x0.w, acc.w);
        acc.x = fmaf(v1, x1.x, acc.x); acc.y = fmaf(v1, x1.y, acc.y);
        acc.z = fmaf(v1, x1.z, acc.z); acc.w = fmaf(v1, x1.w, acc.w);
        acc.x = fmaf(v2, x2.x, acc.x); acc.y = fmaf(v2, x2.y, acc.y);
        acc.z = fmaf(v2, x2.z, acc.z); acc.w = fmaf(v2, x2.w, acc.w);
        acc.x = fmaf(v3, x3.x, acc.x); acc.y = fmaf(v3, x3.y, acc.y);
        acc.z = fmaf(v3, x3.z, acc.z); acc.w = fmaf(v3, x3.w, acc.w);
    }

    acc.x += __shfl_xor(acc.x, 16, 64);
    acc.y += __shfl_xor(acc.y, 16, 64);
    acc.z += __shfl_xor(acc.z, 16, 64);
    acc.w += __shfl_xor(acc.w, 16, 64);
    acc.x += __shfl_xor(acc.x, 32, 64);
    acc.y += __shfl_xor(acc.y, 32, 64);
    acc.z += __shfl_xor(acc.z, 32, 64);
    acc.w += __shfl_xor(acc.w, 32, 64);

    if (lane < 16)
        ((float4*)(out + (size_t)wave * D_FEAT))[f4] = acc;
}

extern "C" void kernel_launch(void* const* d_in, const int* in_sizes, int n_in,
                              void* d_out, int out_size, void* d_ws, size_t ws_size,
                              hipStream_t stream) {
    const int*   rows   = (const int*)d_in[0];
    const int*   cols   = (const int*)d_in[1];
    const float* vals   = (const float*)d_in[2];
    const float* embeds = (const float*)d_in[3];
    float*       out    = (float*)d_out;

    const int n_edges = in_sizes[0];
    const int n_nodes = out_size / D_FEAT;

    int* row_ptr = (int*)d_ws;  // n_nodes+1 ints

    const int build_blocks = (n_edges + BLOCK - 1) / BLOCK;
    const int waves_per_block = BLOCK / 64;
    const int spmm_blocks = (n_nodes + waves_per_block - 1) / waves_per_block;

    // 3x launches: idempotent (pure overwrites), exposes kernel time in dur_us
    // with 2x gain. K_total = (dur - 96us) / 2.
    for (int rep = 0; rep < 3; ++rep) {
        build_row_ptr_edges<<<build_blocks, BLOCK, 0, stream>>>(rows, row_ptr, n_nodes, n_edges);
        spmm_row_strip16<<<spmm_blocks, BLOCK, 0, stream>>>(row_ptr, cols, vals, embeds, out, n_nodes);
    }
}

// Round 8
// 102.472 us; speedup vs baseline: 1.5246x; 1.5246x over previous
//
#include <hip/hip_runtime.h>

// COO SpMM, rows sorted: out[r] = sum_{e: rows[e]==r} vals[e] * embeds[cols[e]]
// N=50000, E=800000, D=64 fp32.
//
// R8 = R7 with the compile fix: __builtin_nontemporal_store needs a native
// clang vector type, not HIP's struct float4. Theory unchanged: harness floor
// ~69us (measured R6), build ~3us, spmm ~26us; spmm invariant to gather bytes
// / instr count / MLP depth => transaction + L2-residency bound. All streaming
// traffic (cols/vals/rows reads, out/row_ptr writes) non-temporal so the
// 4MiB/XCD L2s keep embeds lines.

#define D_FEAT 64
#define BLOCK 256

typedef float f32x4 __attribute__((ext_vector_type(4)));

__global__ __launch_bounds__(BLOCK) void build_row_ptr_edges(
    const int* __restrict__ rows, int* __restrict__ row_ptr,
    int n_nodes, int n_edges)
{
    const int e = blockIdx.x * BLOCK + threadIdx.x;
    if (e >= n_edges) return;
    const int r  = __builtin_nontemporal_load(rows + e);
    const int rp = (e == 0) ? -1 : __builtin_nontemporal_load(rows + e - 1);
    for (int v = rp + 1; v <= r; ++v)
        __builtin_nontemporal_store(e, row_ptr + v);
    if (e == n_edges - 1)
        for (int v = r + 1; v <= n_nodes; ++v)
            __builtin_nontemporal_store(n_edges, row_ptr + v);
}

__global__ __launch_bounds__(BLOCK) void spmm_row_strip16(
    const int* __restrict__ row_ptr,
    const int* __restrict__ cols,
    const float* __restrict__ vals,
    const float* __restrict__ embeds,
    float* __restrict__ out,
    int n_nodes)
{
    const int wave = (int)((blockIdx.x * (unsigned)BLOCK + threadIdx.x) >> 6);
    if (wave >= n_nodes) return;
    const int lane = (int)(threadIdx.x & 63u);
    const int sub  = lane >> 4;   // edge slot 0..3
    const int f4   = lane & 15;   // float4 slot within the 64-float row

    const int s = row_ptr[wave];
    const int t = row_ptr[wave + 1];
    f32x4* const dst = (f32x4*)(out + (size_t)wave * D_FEAT) + f4;
    if (s >= t) {
        if (lane < 16) {
            f32x4 z = {0.f, 0.f, 0.f, 0.f};
            __builtin_nontemporal_store(z, dst);
        }
        return;
    }

    f32x4 acc = {0.f, 0.f, 0.f, 0.f};

    for (int e = s; e < t; e += 16) {
        const int tm1 = t - 1;
        const int i0 = e + sub, i1 = i0 + 4, i2 = i0 + 8, i3 = i0 + 12;
        const int j0 = i0 < tm1 ? i0 : tm1;
        const int j1 = i1 < tm1 ? i1 : tm1;
        const int j2 = i2 < tm1 ? i2 : tm1;
        const int j3 = i3 < tm1 ? i3 : tm1;
        // streaming reads: keep them out of L2 (reserve L2 for embeds)
        const int c0 = __builtin_nontemporal_load(cols + j0);
        const int c1 = __builtin_nontemporal_load(cols + j1);
        const int c2 = __builtin_nontemporal_load(cols + j2);
        const int c3 = __builtin_nontemporal_load(cols + j3);
        float v0 = __builtin_nontemporal_load(vals + j0);
        float v1 = __builtin_nontemporal_load(vals + j1);
        float v2 = __builtin_nontemporal_load(vals + j2);
        float v3 = __builtin_nontemporal_load(vals + j3);
        if (i0 > tm1) v0 = 0.f;
        if (i1 > tm1) v1 = 0.f;
        if (i2 > tm1) v2 = 0.f;
        if (i3 > tm1) v3 = 0.f;
        // 4 independent coalesced 1KiB gathers (these SHOULD cache in L2)
        const f32x4 x0 = ((const f32x4*)(embeds + (size_t)c0 * D_FEAT))[f4];
        const f32x4 x1 = ((const f32x4*)(embeds + (size_t)c1 * D_FEAT))[f4];
        const f32x4 x2 = ((const f32x4*)(embeds + (size_t)c2 * D_FEAT))[f4];
        const f32x4 x3 = ((const f32x4*)(embeds + (size_t)c3 * D_FEAT))[f4];
        acc.x = fmaf(v0, x0.x, acc.x); acc.y = fmaf(v0, x0.y, acc.y);
        acc.z = fmaf(v0, x0.z, acc.z); acc.w = fmaf(v0, x0.w, acc.w);
        acc.x = fmaf(v1, x1.x, acc.x); acc.y = fmaf(v1, x1.y, acc.y);
        acc.z = fmaf(v1, x1.z, acc.z); acc.w = fmaf(v1, x1.w, acc.w);
        acc.x = fmaf(v2, x2.x, acc.x); acc.y = fmaf(v2, x2.y, acc.y);
        acc.z = fmaf(v2, x2.z, acc.z); acc.w = fmaf(v2, x2.w, acc.w);
        acc.x = fmaf(v3, x3.x, acc.x); acc.y = fmaf(v3, x3.y, acc.y);
        acc.z = fmaf(v3, x3.z, acc.z); acc.w = fmaf(v3, x3.w, acc.w);
    }

    acc.x += __shfl_xor(acc.x, 16, 64);
    acc.y += __shfl_xor(acc.y, 16, 64);
    acc.z += __shfl_xor(acc.z, 16, 64);
    acc.w += __shfl_xor(acc.w, 16, 64);
    acc.x += __shfl_xor(acc.x, 32, 64);
    acc.y += __shfl_xor(acc.y, 32, 64);
    acc.z += __shfl_xor(acc.z, 32, 64);
    acc.w += __shfl_xor(acc.w, 32, 64);

    if (lane < 16)
        __builtin_nontemporal_store(acc, dst);
}

extern "C" void kernel_launch(void* const* d_in, const int* in_sizes, int n_in,
                              void* d_out, int out_size, void* d_ws, size_t ws_size,
                              hipStream_t stream) {
    const int*   rows   = (const int*)d_in[0];
    const int*   cols   = (const int*)d_in[1];
    const float* vals   = (const float*)d_in[2];
    const float* embeds = (const float*)d_in[3];
    float*       out    = (float*)d_out;

    const int n_edges = in_sizes[0];
    const int n_nodes = out_size / D_FEAT;

    int* row_ptr = (int*)d_ws;  // n_nodes+1 ints

    {
        const int nblocks = (n_edges + BLOCK - 1) / BLOCK;
        build_row_ptr_edges<<<nblocks, BLOCK, 0, stream>>>(rows, row_ptr, n_nodes, n_edges);
    }
    {
        const int waves_per_block = BLOCK / 64;
        const int nblocks = (n_nodes + waves_per_block - 1) / waves_per_block;
        spmm_row_strip16<<<nblocks, BLOCK, 0, stream>>>(row_ptr, cols, vals, embeds, out, n_nodes);
    }
}

// Round 9
// 99.911 us; speedup vs baseline: 1.5637x; 1.0256x over previous
//
#include <hip/hip_runtime.h>

// COO SpMM, rows sorted: out[r] = sum_{e: rows[e]==r} vals[e] * embeds[cols[e]]
// N=50000, E=800000, D=64 fp32.
//
// R9: NT loads reverted (R8 showed they regress: cols/vals 64B lines are
// reused across the 4 strip loads; NT defeats that). NT stores kept for
// out/row_ptr: write-allocate pollution (12.8MB never-re-read lines) evicts
// embeds from the 4MiB/XCD L2s.
// Established by measurement (R2-R8): harness floor ~69us; build ~3us;
// spmm ~26us and invariant to gather bytes (fp16 null), gather instruction
// count, and MLP depth => random-gather transaction/fabric floor ~8TB/s
// effective through L2/L3.

#define D_FEAT 64
#define BLOCK 256

typedef float f32x4 __attribute__((ext_vector_type(4)));

__global__ __launch_bounds__(BLOCK) void build_row_ptr_edges(
    const int* __restrict__ rows, int* __restrict__ row_ptr,
    int n_nodes, int n_edges)
{
    const int e = blockIdx.x * BLOCK + threadIdx.x;
    if (e >= n_edges) return;
    const int r  = rows[e];
    const int rp = (e == 0) ? -1 : rows[e - 1];
    for (int v = rp + 1; v <= r; ++v)
        __builtin_nontemporal_store(e, row_ptr + v);
    if (e == n_edges - 1)
        for (int v = r + 1; v <= n_nodes; ++v)
            __builtin_nontemporal_store(n_edges, row_ptr + v);
}

__global__ __launch_bounds__(BLOCK) void spmm_row_strip16(
    const int* __restrict__ row_ptr,
    const int* __restrict__ cols,
    const float* __restrict__ vals,
    const float* __restrict__ embeds,
    float* __restrict__ out,
    int n_nodes)
{
    const int wave = (int)((blockIdx.x * (unsigned)BLOCK + threadIdx.x) >> 6);
    if (wave >= n_nodes) return;
    const int lane = (int)(threadIdx.x & 63u);
    const int sub  = lane >> 4;   // edge slot 0..3
    const int f4   = lane & 15;   // float4 slot within the 64-float row

    const int s = row_ptr[wave];
    const int t = row_ptr[wave + 1];
    f32x4* const dst = (f32x4*)(out + (size_t)wave * D_FEAT) + f4;
    if (s >= t) {
        if (lane < 16) {
            f32x4 z = {0.f, 0.f, 0.f, 0.f};
            __builtin_nontemporal_store(z, dst);
        }
        return;
    }

    f32x4 acc = {0.f, 0.f, 0.f, 0.f};

    for (int e = s; e < t; e += 16) {
        const int tm1 = t - 1;
        const int i0 = e + sub, i1 = i0 + 4, i2 = i0 + 8, i3 = i0 + 12;
        const int j0 = i0 < tm1 ? i0 : tm1;
        const int j1 = i1 < tm1 ? i1 : tm1;
        const int j2 = i2 < tm1 ? i2 : tm1;
        const int j3 = i3 < tm1 ? i3 : tm1;
        // cached reads: 64B lines reused across the 4 slot-loads of a strip
        const int c0 = cols[j0], c1 = cols[j1], c2 = cols[j2], c3 = cols[j3];
        float v0 = vals[j0], v1 = vals[j1], v2 = vals[j2], v3 = vals[j3];
        if (i0 > tm1) v0 = 0.f;
        if (i1 > tm1) v1 = 0.f;
        if (i2 > tm1) v2 = 0.f;
        if (i3 > tm1) v3 = 0.f;
        // 4 independent coalesced 1KiB gathers (want these resident in L2)
        const f32x4 x0 = ((const f32x4*)(embeds + (size_t)c0 * D_FEAT))[f4];
        const f32x4 x1 = ((const f32x4*)(embeds + (size_t)c1 * D_FEAT))[f4];
        const f32x4 x2 = ((const f32x4*)(embeds + (size_t)c2 * D_FEAT))[f4];
        const f32x4 x3 = ((const f32x4*)(embeds + (size_t)c3 * D_FEAT))[f4];
        acc.x = fmaf(v0, x0.x, acc.x); acc.y = fmaf(v0, x0.y, acc.y);
        acc.z = fmaf(v0, x0.z, acc.z); acc.w = fmaf(v0, x0.w, acc.w);
        acc.x = fmaf(v1, x1.x, acc.x); acc.y = fmaf(v1, x1.y, acc.y);
        acc.z = fmaf(v1, x1.z, acc.z); acc.w = fmaf(v1, x1.w, acc.w);
        acc.x = fmaf(v2, x2.x, acc.x); acc.y = fmaf(v2, x2.y, acc.y);
        acc.z = fmaf(v2, x2.z, acc.z); acc.w = fmaf(v2, x2.w, acc.w);
        acc.x = fmaf(v3, x3.x, acc.x); acc.y = fmaf(v3, x3.y, acc.y);
        acc.z = fmaf(v3, x3.z, acc.z); acc.w = fmaf(v3, x3.w, acc.w);
    }

    acc.x += __shfl_xor(acc.x, 16, 64);
    acc.y += __shfl_xor(acc.y, 16, 64);
    acc.z += __shfl_xor(acc.z, 16, 64);
    acc.w += __shfl_xor(acc.w, 16, 64);
    acc.x += __shfl_xor(acc.x, 32, 64);
    acc.y += __shfl_xor(acc.y, 32, 64);
    acc.z += __shfl_xor(acc.z, 32, 64);
    acc.w += __shfl_xor(acc.w, 32, 64);

    if (lane < 16)
        __builtin_nontemporal_store(acc, dst);
}

extern "C" void kernel_launch(void* const* d_in, const int* in_sizes, int n_in,
                              void* d_out, int out_size, void* d_ws, size_t ws_size,
                              hipStream_t stream) {
    const int*   rows   = (const int*)d_in[0];
    const int*   cols   = (const int*)d_in[1];
    const float* vals   = (const float*)d_in[2];
    const float* embeds = (const float*)d_in[3];
    float*       out    = (float*)d_out;

    const int n_edges = in_sizes[0];
    const int n_nodes = out_size / D_FEAT;

    int* row_ptr = (int*)d_ws;  // n_nodes+1 ints

    {
        const int nblocks = (n_edges + BLOCK - 1) / BLOCK;
        build_row_ptr_edges<<<nblocks, BLOCK, 0, stream>>>(rows, row_ptr, n_nodes, n_edges);
    }
    {
        const int waves_per_block = BLOCK / 64;
        const int nblocks = (n_nodes + waves_per_block - 1) / waves_per_block;
        spmm_row_strip16<<<nblocks, BLOCK, 0, stream>>>(row_ptr, cols, vals, embeds, out, n_nodes);
    }
}